// Round 2
// baseline (251.141 us; speedup 1.0000x reference)
//
#include <hip/hip_runtime.h>
#include <hip/hip_bf16.h>

#define Bb 2
#define Nn 32
#define Tt 32
#define Mm 256
#define Ll 20
#define Hh 128
#define Dd 128
#define TAUu 64
#define RSQRT_D 0.08838834764831843f

// ---------------- Kernel 1: polyline/map encoder ----------------
// grid = B*M blocks, 128 threads (one per hidden unit)
__global__ __launch_bounds__(128) void k_map(
    const float* __restrict__ poly, const float* __restrict__ pmask,
    const int* __restrict__ ptype, const int* __restrict__ ptl, const int* __restrict__ proute,
    const float* __restrict__ pm_w1, const float* __restrict__ pm_b1,
    const float* __restrict__ pm_w2, const float* __restrict__ pm_b2,
    const float* __restrict__ type_emb, const float* __restrict__ tl_emb, const float* __restrict__ route_emb,
    const float* __restrict__ mo_w1, const float* __restrict__ mo_b1,
    const float* __restrict__ mo_w2, const float* __restrict__ mo_b2,
    float* __restrict__ map_node, float* __restrict__ map_center)
{
    int bm = blockIdx.x;
    int h  = threadIdx.x;
    __shared__ float pts[Ll*2];
    __shared__ float h1[Hh];
    __shared__ float hv[Hh];
    if (h < Ll*2) pts[h] = poly[bm*Ll*2 + h];
    __syncthreads();
    float w1x = pm_w1[h];
    float w1y = pm_w1[Hh+h];
    float bb1 = pm_b1[h];
    float bb2 = pm_b2[h];
    float mx = -1e30f;
    for (int l = 0; l < Ll; ++l) {
        float x = pts[2*l], y = pts[2*l+1];
        h1[h] = fmaxf(w1x*x + w1y*y + bb1, 0.f);
        __syncthreads();
        float acc = bb2;
        for (int k = 0; k < Hh; ++k) acc += h1[k] * pm_w2[k*Hh + h];
        mx = fmaxf(mx, fmaxf(acc, 0.f));
        __syncthreads();
    }
    int ti = min(max(ptype[bm], 0), 3);
    int si = min(max(ptl[bm], 0), 7);
    int ri = min(max(proute[bm], 0), 1);
    hv[h] = mx + type_emb[ti*Hh+h] + tl_emb[si*Hh+h] + route_emb[ri*Hh+h];
    __syncthreads();
    float acc = mo_b1[h];
    for (int k = 0; k < Hh; ++k) acc += hv[k]*mo_w1[k*Hh+h];
    float g = fmaxf(acc, 0.f);
    __syncthreads();
    h1[h] = g;
    __syncthreads();
    float acc2 = mo_b2[h];
    for (int k = 0; k < Hh; ++k) acc2 += h1[k]*mo_w2[k*Dd+h];
    float mk = (pmask[bm] > 0.5f) ? 1.f : 0.f;
    map_node[bm*Dd + h] = acc2 * mk;
    if (h == 0) {
        float sx = 0.f, sy = 0.f;
        for (int l = 0; l < Ll; ++l) { sx += pts[2*l]; sy += pts[2*l+1]; }
        map_center[bm*2+0] = sx / (float)Ll;
        map_center[bm*2+1] = sy / (float)Ll;
    }
}

// ---------------- Kernel 2: agent embedding ----------------
// grid = B*N*T blocks, 128 threads
__global__ __launch_bounds__(128) void k_agent(
    const float* __restrict__ astate, const float* __restrict__ amask,
    const float* __restrict__ ae_w1, const float* __restrict__ ae_b1,
    const float* __restrict__ ae_w2, const float* __restrict__ ae_b2,
    const float* __restrict__ ae_w3, const float* __restrict__ ae_b3,
    float* __restrict__ a_emb)
{
    int r = blockIdx.x;
    int h = threadIdx.x;
    __shared__ float f5[5];
    __shared__ float a1[Hh];
    if (h < 5) f5[h] = astate[r*5 + h];
    __syncthreads();
    float acc = ae_b1[h];
    for (int k = 0; k < 5; ++k) acc += f5[k]*ae_w1[k*Hh+h];
    a1[h] = fmaxf(acc, 0.f);
    __syncthreads();
    float acc2 = ae_b2[h];
    for (int k = 0; k < Hh; ++k) acc2 += a1[k]*ae_w2[k*Hh+h];
    float v2 = fmaxf(acc2, 0.f);
    __syncthreads();
    a1[h] = v2;
    __syncthreads();
    float acc3 = ae_b3[h];
    for (int k = 0; k < Hh; ++k) acc3 += a1[k]*ae_w3[k*Dd+h];
    float mk = (amask[r] > 0.5f) ? 1.f : 0.f;
    a_emb[r*Dd + h] = acc3 * mk;
}

// ---------------- Kernel 3: map attention ----------------
// grid = B*N*T blocks, 256 threads (one per map polyline; M==256)
__global__ __launch_bounds__(256) void k_mapattn(
    const float* __restrict__ astate, const float* __restrict__ pmask,
    const float* __restrict__ a_emb, const float* __restrict__ map_node,
    const float* __restrict__ map_center,
    const float* __restrict__ mr_w1, const float* __restrict__ mr_b1,
    const float* __restrict__ mr_w2, const float* __restrict__ mr_b2,
    float* __restrict__ map_ctx)
{
    int r = blockIdx.x;
    int b = r / (Nn*Tt);
    int tid = threadIdx.x;
    __shared__ float ae[Dd];
    __shared__ float w1[3*Hh];
    __shared__ float b1s[Hh];
    __shared__ float w2[Hh];
    __shared__ float lg[Mm];
    __shared__ float red[256];
    if (tid < Dd) ae[tid] = a_emb[r*Dd + tid];
    for (int q = tid; q < 3*Hh; q += 256) w1[q] = mr_w1[q];
    if (tid < Hh) { b1s[tid] = mr_b1[tid]; w2[tid] = mr_w2[tid]; }
    float px = astate[r*5+0];
    float py = astate[r*5+1];
    float b2c = mr_b2[0];
    __syncthreads();

    int m = tid;  // M == blockDim
    float cx = map_center[(b*Mm+m)*2+0];
    float cy = map_center[(b*Mm+m)*2+1];
    float rx = cx - px, ry = cy - py;
    float dd = sqrtf(rx*rx + ry*ry);
    float s = b2c;
    for (int hh = 0; hh < Hh; ++hh) {
        float t1 = fmaxf(rx*w1[hh] + ry*w1[Hh+hh] + dd*w1[2*Hh+hh] + b1s[hh], 0.f);
        s += t1 * w2[hh];
    }
    const float* mn = map_node + (b*Mm+m)*Dd;
    float dot = 0.f;
    for (int d = 0; d < Dd; ++d) dot += ae[d]*mn[d];
    bool mk = pmask[b*Mm+m] > 0.5f;
    lg[m] = mk ? (dot*RSQRT_D + s) : -1e30f;
    __syncthreads();

    // block softmax over 256 logits
    red[tid] = lg[tid];
    __syncthreads();
    for (int off = 128; off > 0; off >>= 1) {
        if (tid < off) red[tid] = fmaxf(red[tid], red[tid+off]);
        __syncthreads();
    }
    float mxv = red[0];
    __syncthreads();
    float e = (lg[tid] > -1e29f) ? expf(lg[tid]-mxv) : 0.f;
    red[tid] = e;
    __syncthreads();
    for (int off = 128; off > 0; off >>= 1) {
        if (tid < off) red[tid] += red[tid+off];
        __syncthreads();
    }
    float sm = red[0];
    float p = e / fmaxf(sm, 1e-9f);
    __syncthreads();
    lg[tid] = p;
    __syncthreads();

    if (tid < Dd) {
        float acc = 0.f;
        for (int m2 = 0; m2 < Mm; ++m2) acc += lg[m2]*map_node[(b*Mm+m2)*Dd + tid];
        map_ctx[r*Dd + tid] = acc;
    }
}

// ---------------- Kernel 4: neighbor attention + output MLP ----------------
// grid = B*N*T blocks, 128 threads
__global__ __launch_bounds__(128) void k_nbr_out(
    const float* __restrict__ astate, const float* __restrict__ amask,
    const float* __restrict__ a_emb, const float* __restrict__ map_ctx,
    const float* __restrict__ nr_w1, const float* __restrict__ nr_b1,
    const float* __restrict__ nr_w2, const float* __restrict__ nr_b2,
    const float* __restrict__ to_w1, const float* __restrict__ to_b1,
    const float* __restrict__ to_w2, const float* __restrict__ to_b2,
    float* __restrict__ out)
{
    int r = blockIdx.x;
    int b = r / (Nn*Tt);
    int i = (r / Tt) % Nn;
    int t = r % Tt;
    int tid = threadIdx.x;
    __shared__ float ei[Dd];
    __shared__ float w1[5*Hh];
    __shared__ float b1s[Hh];
    __shared__ float w2[Hh];
    __shared__ float lgn[Nn];
    __shared__ float pj[Nn];
    __shared__ float tauv[3*Dd];
    __shared__ float g1[Hh];
    ei[tid] = a_emb[r*Dd + tid];
    for (int q = tid; q < 5*Hh; q += 128) w1[q] = nr_w1[q];
    b1s[tid] = nr_b1[tid];
    w2[tid]  = nr_w2[tid];
    float pxi = astate[r*5+0];
    float pyi = astate[r*5+1];
    float vxi = astate[r*5+3];
    float vyi = astate[r*5+4];
    bool  vi  = amask[r] > 0.5f;
    float b2c = nr_b2[0];
    __syncthreads();

    if (tid < Nn) {
        int j  = tid;
        int rj = (b*Nn + j)*Tt + t;
        float pxj = astate[rj*5+0];
        float pyj = astate[rj*5+1];
        float vxj = astate[rj*5+3];
        float vyj = astate[rj*5+4];
        float rpx = pxj-pxi, rpy = pyj-pyi, rvx = vxj-vxi, rvy = vyj-vyi;
        float dd  = sqrtf(rpx*rpx + rpy*rpy);
        float s = b2c;
        for (int hh = 0; hh < Hh; ++hh) {
            float t1 = fmaxf(rpx*w1[hh] + rpy*w1[Hh+hh] + rvx*w1[2*Hh+hh]
                             + rvy*w1[3*Hh+hh] + dd*w1[4*Hh+hh] + b1s[hh], 0.f);
            s += t1 * w2[hh];
        }
        const float* ej = a_emb + (size_t)rj*Dd;
        float dot = 0.f;
        for (int d = 0; d < Dd; ++d) dot += ei[d]*ej[d];
        bool vj = amask[rj] > 0.5f;
        bool ok = vi && vj && (dd <= 30.0f) && (j != i);
        lgn[j] = ok ? (dot*RSQRT_D + s) : -1e30f;
    }
    __syncthreads();
    if (tid < Nn) {
        float mxv = -1e30f;
        for (int j = 0; j < Nn; ++j) mxv = fmaxf(mxv, lgn[j]);
        float sm = 0.f;
        for (int j = 0; j < Nn; ++j) sm += (lgn[j] > -1e29f) ? expf(lgn[j]-mxv) : 0.f;
        float inv = 1.f / fmaxf(sm, 1e-9f);
        pj[tid] = ((lgn[tid] > -1e29f) ? expf(lgn[tid]-mxv) : 0.f) * inv;
    }
    __syncthreads();

    float nctx = 0.f;
    for (int j = 0; j < Nn; ++j) nctx += pj[j]*a_emb[((b*Nn+j)*Tt+t)*Dd + tid];
    tauv[tid]       = ei[tid];
    tauv[Dd+tid]    = map_ctx[r*Dd + tid];
    tauv[2*Dd+tid]  = nctx;
    __syncthreads();

    float acc1 = to_b1[tid];
    for (int k = 0; k < 3*Dd; ++k) acc1 += tauv[k]*to_w1[k*Hh+tid];
    g1[tid] = fmaxf(acc1, 0.f);
    __syncthreads();

    if (tid < TAUu) {
        float o = to_b2[tid];
        for (int hh = 0; hh < Hh; ++hh) o += g1[hh]*to_w2[hh*TAUu+tid];
        o *= vi ? 1.f : 0.f;
        out[r*TAUu + tid] = o;
    }
}

extern "C" void kernel_launch(void* const* d_in, const int* in_sizes, int n_in,
                              void* d_out, int out_size, void* d_ws, size_t ws_size,
                              hipStream_t stream) {
    const float* agents_state  = (const float*)d_in[0];
    const float* agents_mask   = (const float*)d_in[1];
    const float* map_polylines = (const float*)d_in[2];
    const float* map_poly_mask = (const float*)d_in[3];
    const int*   map_poly_type = (const int*)d_in[4];
    const int*   map_tl_status = (const int*)d_in[5];
    const int*   map_on_route  = (const int*)d_in[6];
    const float* pm_w1 = (const float*)d_in[7];
    const float* pm_b1 = (const float*)d_in[8];
    const float* pm_w2 = (const float*)d_in[9];
    const float* pm_b2 = (const float*)d_in[10];
    const float* type_emb  = (const float*)d_in[11];
    const float* tl_emb    = (const float*)d_in[12];
    const float* route_emb = (const float*)d_in[13];
    const float* mo_w1 = (const float*)d_in[14];
    const float* mo_b1 = (const float*)d_in[15];
    const float* mo_w2 = (const float*)d_in[16];
    const float* mo_b2 = (const float*)d_in[17];
    const float* ae_w1 = (const float*)d_in[18];
    const float* ae_b1 = (const float*)d_in[19];
    const float* ae_w2 = (const float*)d_in[20];
    const float* ae_b2 = (const float*)d_in[21];
    const float* ae_w3 = (const float*)d_in[22];
    const float* ae_b3 = (const float*)d_in[23];
    const float* mr_w1 = (const float*)d_in[24];
    const float* mr_b1 = (const float*)d_in[25];
    const float* mr_w2 = (const float*)d_in[26];
    const float* mr_b2 = (const float*)d_in[27];
    const float* nr_w1 = (const float*)d_in[28];
    const float* nr_b1 = (const float*)d_in[29];
    const float* nr_w2 = (const float*)d_in[30];
    const float* nr_b2 = (const float*)d_in[31];
    const float* to_w1 = (const float*)d_in[32];
    const float* to_b1 = (const float*)d_in[33];
    const float* to_w2 = (const float*)d_in[34];
    const float* to_b2 = (const float*)d_in[35];

    float* ws = (float*)d_ws;
    float* map_node   = ws;                          // B*M*D      = 65536
    float* map_center = ws + 65536;                  // B*M*2      = 1024
    float* a_emb      = ws + 66560;                  // B*N*T*D    = 262144
    float* map_ctx    = ws + 328704;                 // B*N*T*D    = 262144

    float* out = (float*)d_out;

    k_map<<<Bb*Mm, 128, 0, stream>>>(map_polylines, map_poly_mask,
        map_poly_type, map_tl_status, map_on_route,
        pm_w1, pm_b1, pm_w2, pm_b2, type_emb, tl_emb, route_emb,
        mo_w1, mo_b1, mo_w2, mo_b2, map_node, map_center);

    k_agent<<<Bb*Nn*Tt, 128, 0, stream>>>(agents_state, agents_mask,
        ae_w1, ae_b1, ae_w2, ae_b2, ae_w3, ae_b3, a_emb);

    k_mapattn<<<Bb*Nn*Tt, 256, 0, stream>>>(agents_state, map_poly_mask,
        a_emb, map_node, map_center, mr_w1, mr_b1, mr_w2, mr_b2, map_ctx);

    k_nbr_out<<<Bb*Nn*Tt, 128, 0, stream>>>(agents_state, agents_mask,
        a_emb, map_ctx, nr_w1, nr_b1, nr_w2, nr_b2,
        to_w1, to_b1, to_w2, to_b2, out);
}

// Round 3
// 202.355 us; speedup vs baseline: 1.2411x; 1.2411x over previous
//
#include <hip/hip_runtime.h>
#include <hip/hip_bf16.h>

#define Bb 2
#define Nn 32
#define Tt 32
#define Mm 256
#define Ll 20
#define Hh 128
#define Dd 128
#define TAUu 64
#define RSQRT_D 0.08838834764831843f

// ================= Kernel 1: polyline/map encoder =================
// grid = B*M = 512 blocks, 256 threads. half = tid>>7 splits the 20 polyline
// points 10/10; k-loop amortizes each pm_w2 load over 10 accumulators.
__global__ __launch_bounds__(256) void k_map(
    const float* __restrict__ poly, const float* __restrict__ pmask,
    const int* __restrict__ ptype, const int* __restrict__ ptl, const int* __restrict__ proute,
    const float* __restrict__ pm_w1, const float* __restrict__ pm_b1,
    const float* __restrict__ pm_w2, const float* __restrict__ pm_b2,
    const float* __restrict__ type_emb, const float* __restrict__ tl_emb, const float* __restrict__ route_emb,
    const float* __restrict__ mo_w1, const float* __restrict__ mo_b1,
    const float* __restrict__ mo_w2, const float* __restrict__ mo_b2,
    float* __restrict__ map_node, float* __restrict__ map_nodeT, float* __restrict__ map_center)
{
    int bm = blockIdx.x;
    int b  = bm >> 8;
    int m  = bm & 255;
    int tid = threadIdx.x;
    int h    = tid & 127;
    int half = tid >> 7;
    __shared__ float pts[Ll*2];
    __shared__ float h1a[Ll][Hh];
    __shared__ float hv[Hh];
    __shared__ float red[Hh];
    if (tid < Ll*2) pts[tid] = poly[bm*Ll*2 + tid];
    __syncthreads();
    float w1x = pm_w1[h];
    float w1y = pm_w1[Hh+h];
    float bb1 = pm_b1[h];
    int l0 = half*10;
    #pragma unroll
    for (int u = 0; u < 10; ++u) {
        int l = l0 + u;
        h1a[l][h] = fmaxf(fmaf(w1x, pts[2*l], fmaf(w1y, pts[2*l+1], bb1)), 0.f);
    }
    __syncthreads();
    float bb2 = pm_b2[h];
    float acc[10];
    #pragma unroll
    for (int u = 0; u < 10; ++u) acc[u] = bb2;
    for (int k = 0; k < Hh; ++k) {
        float w = pm_w2[k*Hh + h];
        #pragma unroll
        for (int u = 0; u < 10; ++u) acc[u] = fmaf(h1a[l0+u][k], w, acc[u]);
    }
    float mx = 0.f;  // relu floor: max(relu(x_l)) == max(0, max(x_l))
    #pragma unroll
    for (int u = 0; u < 10; ++u) mx = fmaxf(mx, acc[u]);
    if (half == 1) red[h] = mx;
    __syncthreads();
    if (half == 0) {
        float mm2 = fmaxf(mx, red[h]);
        int ti = min(max(ptype[bm], 0), 3);
        int si = min(max(ptl[bm], 0), 7);
        int ri = min(max(proute[bm], 0), 1);
        hv[h] = mm2 + type_emb[ti*Hh+h] + tl_emb[si*Hh+h] + route_emb[ri*Hh+h];
    }
    __syncthreads();
    // mo layer1, k split between halves
    float a1 = 0.f;
    for (int k = half*64; k < half*64 + 64; ++k) a1 = fmaf(hv[k], mo_w1[k*Hh+h], a1);
    if (half == 1) red[h] = a1;
    __syncthreads();
    if (half == 0) hv[h] = fmaxf(a1 + red[h] + mo_b1[h], 0.f);
    __syncthreads();
    float a2 = 0.f;
    for (int k = half*64; k < half*64 + 64; ++k) a2 = fmaf(hv[k], mo_w2[k*Dd+h], a2);
    if (half == 1) red[h] = a2;
    __syncthreads();
    if (half == 0) {
        float val = a2 + red[h] + mo_b2[h];
        float mk = (pmask[bm] > 0.5f) ? 1.f : 0.f;
        val *= mk;
        map_node[bm*Dd + h] = val;
        map_nodeT[(b*Dd + h)*Mm + m] = val;
    }
    if (tid == 0) {
        float sx = 0.f, sy = 0.f;
        for (int l = 0; l < Ll; ++l) { sx += pts[2*l]; sy += pts[2*l+1]; }
        map_center[bm*2+0] = sx / (float)Ll;
        map_center[bm*2+1] = sy / (float)Ll;
    }
}

// ================= Kernel 2: agent embedding =================
// grid = B*N*T/4 = 512 blocks, 128 threads; 4 rows per block (weights amortized).
__global__ __launch_bounds__(128) void k_agent(
    const float* __restrict__ astate, const float* __restrict__ amask,
    const float* __restrict__ ae_w1, const float* __restrict__ ae_b1,
    const float* __restrict__ ae_w2, const float* __restrict__ ae_b2,
    const float* __restrict__ ae_w3, const float* __restrict__ ae_b3,
    float* __restrict__ a_emb)
{
    int r0 = blockIdx.x * 4;
    int h  = threadIdx.x;
    __shared__ float f5[4][5];
    __shared__ float a1s[4][Hh];
    if (h < 20) f5[h/5][h%5] = astate[(r0 + h/5)*5 + (h%5)];
    __syncthreads();
    float acc[4];
    float b1v = ae_b1[h];
    #pragma unroll
    for (int r = 0; r < 4; ++r) acc[r] = b1v;
    #pragma unroll
    for (int k = 0; k < 5; ++k) {
        float w = ae_w1[k*Hh + h];
        #pragma unroll
        for (int r = 0; r < 4; ++r) acc[r] = fmaf(f5[r][k], w, acc[r]);
    }
    #pragma unroll
    for (int r = 0; r < 4; ++r) a1s[r][h] = fmaxf(acc[r], 0.f);
    __syncthreads();
    float b2v = ae_b2[h];
    #pragma unroll
    for (int r = 0; r < 4; ++r) acc[r] = b2v;
    for (int k = 0; k < Hh; ++k) {
        float w = ae_w2[k*Hh + h];
        #pragma unroll
        for (int r = 0; r < 4; ++r) acc[r] = fmaf(a1s[r][k], w, acc[r]);
    }
    float v2[4];
    #pragma unroll
    for (int r = 0; r < 4; ++r) v2[r] = fmaxf(acc[r], 0.f);
    __syncthreads();
    #pragma unroll
    for (int r = 0; r < 4; ++r) a1s[r][h] = v2[r];
    __syncthreads();
    float b3v = ae_b3[h];
    #pragma unroll
    for (int r = 0; r < 4; ++r) acc[r] = b3v;
    for (int k = 0; k < Hh; ++k) {
        float w = ae_w3[k*Dd + h];
        #pragma unroll
        for (int r = 0; r < 4; ++r) acc[r] = fmaf(a1s[r][k], w, acc[r]);
    }
    #pragma unroll
    for (int r = 0; r < 4; ++r) {
        float mk = (amask[r0+r] > 0.5f) ? 1.f : 0.f;
        a_emb[(r0+r)*Dd + h] = acc[r] * mk;
    }
}

// ================= Kernel 3: map attention =================
// grid = 512 blocks, 256 threads; 4 consecutive rows (same b) per block.
// map_nodeT gives lane-coalesced dot loads; wave-per-row shfl softmax.
__global__ __launch_bounds__(256) void k_mapattn(
    const float* __restrict__ astate, const float* __restrict__ pmask,
    const float* __restrict__ a_emb, const float* __restrict__ map_node,
    const float* __restrict__ map_nodeT, const float* __restrict__ map_center,
    const float* __restrict__ mr_w1, const float* __restrict__ mr_b1,
    const float* __restrict__ mr_w2, const float* __restrict__ mr_b2,
    float* __restrict__ map_ctx)
{
    int r0  = blockIdx.x * 4;
    int b   = r0 >> 10;
    int tid = threadIdx.x;
    __shared__ float w1m[3*Hh];
    __shared__ float b1m[Hh];
    __shared__ float w2m[Hh];
    __shared__ float pxy4[4][2];
    __shared__ float ae4[4][Dd];
    __shared__ float lg4[4][Mm];      // logits, then reused as probabilities
    __shared__ float redc[4][Dd];
    for (int q = tid; q < 3*Hh; q += 256) w1m[q] = mr_w1[q];
    if (tid < Hh) { b1m[tid] = mr_b1[tid]; w2m[tid] = mr_w2[tid]; }
    for (int q = tid; q < 512; q += 256) ae4[q>>7][q&127] = a_emb[(r0 + (q>>7))*Dd + (q&127)];
    if (tid < 8) pxy4[tid>>1][tid&1] = astate[(r0 + (tid>>1))*5 + (tid&1)];
    float b2c = mr_b2[0];
    __syncthreads();

    // Phase B: per-m logits for 4 rows
    {
        int m = tid;
        float cx = map_center[(b*Mm+m)*2+0];
        float cy = map_center[(b*Mm+m)*2+1];
        float rx[4], ry[4], dv[4], sA[4], dt[4];
        #pragma unroll
        for (int r = 0; r < 4; ++r) {
            rx[r] = cx - pxy4[r][0];
            ry[r] = cy - pxy4[r][1];
            dv[r] = sqrtf(rx[r]*rx[r] + ry[r]*ry[r]);
            sA[r] = b2c;
            dt[r] = 0.f;
        }
        for (int hh = 0; hh < Hh; ++hh) {
            float wa = w1m[hh], wb = w1m[Hh+hh], wc = w1m[2*Hh+hh];
            float bbv = b1m[hh], w2v = w2m[hh];
            #pragma unroll
            for (int r = 0; r < 4; ++r) {
                float t1 = fmaxf(fmaf(rx[r], wa, fmaf(ry[r], wb, fmaf(dv[r], wc, bbv))), 0.f);
                sA[r] = fmaf(t1, w2v, sA[r]);
            }
        }
        for (int d = 0; d < Dd; ++d) {
            float v = map_nodeT[(b*Dd + d)*Mm + m];
            #pragma unroll
            for (int r = 0; r < 4; ++r) dt[r] = fmaf(ae4[r][d], v, dt[r]);
        }
        bool mk = pmask[b*Mm+m] > 0.5f;
        #pragma unroll
        for (int r = 0; r < 4; ++r)
            lg4[r][m] = mk ? fmaf(dt[r], RSQRT_D, sA[r]) : -1e30f;
    }
    __syncthreads();

    // Phase C: softmax, wave w handles row w (no barriers inside)
    {
        int w = tid >> 6, lam = tid & 63;
        float x0 = lg4[w][lam], x1 = lg4[w][64+lam], x2 = lg4[w][128+lam], x3 = lg4[w][192+lam];
        float mxv = fmaxf(fmaxf(x0,x1), fmaxf(x2,x3));
        for (int off = 32; off; off >>= 1) mxv = fmaxf(mxv, __shfl_xor(mxv, off));
        float e0 = (x0 > -1e29f) ? expf(x0-mxv) : 0.f;
        float e1 = (x1 > -1e29f) ? expf(x1-mxv) : 0.f;
        float e2 = (x2 > -1e29f) ? expf(x2-mxv) : 0.f;
        float e3 = (x3 > -1e29f) ? expf(x3-mxv) : 0.f;
        float sm = e0+e1+e2+e3;
        for (int off = 32; off; off >>= 1) sm += __shfl_xor(sm, off);
        float inv = 1.f / fmaxf(sm, 1e-9f);
        lg4[w][lam]     = e0*inv;
        lg4[w][64+lam]  = e1*inv;
        lg4[w][128+lam] = e2*inv;
        lg4[w][192+lam] = e3*inv;
    }
    __syncthreads();

    // Phase D: ctx = p @ map_node, m-range split between halves
    {
        int d = tid & 127, hf = tid >> 7;
        float acc[4] = {0.f, 0.f, 0.f, 0.f};
        for (int mm = 0; mm < 128; ++mm) {
            int m2 = (hf<<7) + mm;
            float v = map_node[(b*Mm+m2)*Dd + d];
            #pragma unroll
            for (int r = 0; r < 4; ++r) acc[r] = fmaf(lg4[r][m2], v, acc[r]);
        }
        if (hf == 1) {
            #pragma unroll
            for (int r = 0; r < 4; ++r) redc[r][d] = acc[r];
        }
        __syncthreads();
        if (hf == 0) {
            #pragma unroll
            for (int r = 0; r < 4; ++r) map_ctx[(r0+r)*Dd + d] = acc[r] + redc[r][d];
        }
    }
}

// ================= Kernel 4: neighbor attention + output MLP =================
// grid = 512 blocks, 256 threads; 4 rows (same b,i; t0..t0+3) per block.
__global__ __launch_bounds__(256) void k_nbr_out(
    const float* __restrict__ astate, const float* __restrict__ amask,
    const float* __restrict__ a_emb, const float* __restrict__ map_ctx,
    const float* __restrict__ nr_w1, const float* __restrict__ nr_b1,
    const float* __restrict__ nr_w2, const float* __restrict__ nr_b2,
    const float* __restrict__ to_w1, const float* __restrict__ to_b1,
    const float* __restrict__ to_w2, const float* __restrict__ to_b2,
    float* __restrict__ out)
{
    int r0 = blockIdx.x * 4;
    int b  = r0 >> 10;
    int i  = (r0 >> 5) & 31;
    int t0 = r0 & 31;
    int tid = threadIdx.x;
    __shared__ float w1n[5*Hh];
    __shared__ float b1n[Hh];
    __shared__ float w2n[Hh];
    __shared__ float ei4[4][Dd];
    __shared__ float tau[4][3*Dd];
    __shared__ float jdat[4][Nn][5];   // px,py,vx,vy,mask at row's t
    __shared__ float rowdat[4][5];
    __shared__ float lgn[4][Nn];       // logits, then probabilities
    __shared__ float g1s[4][Hh];
    __shared__ float redn[4][Dd];

    for (int q = tid; q < 5*Hh; q += 256) w1n[q] = nr_w1[q];
    if (tid < Hh) { b1n[tid] = nr_b1[tid]; w2n[tid] = nr_w2[tid]; }
    for (int q = tid; q < 512; q += 256) {
        int rr = q>>7, d = q&127;
        float v = a_emb[(r0+rr)*Dd + d];
        ei4[rr][d] = v;
        tau[rr][d] = v;
        tau[rr][Dd + d] = map_ctx[(r0+rr)*Dd + d];
    }
    if (tid < 128) {
        int rr = tid >> 5, j = tid & 31;
        int rj = ((b*Nn + j)*Tt + t0 + rr);
        jdat[rr][j][0] = astate[rj*5+0];
        jdat[rr][j][1] = astate[rj*5+1];
        jdat[rr][j][2] = astate[rj*5+3];
        jdat[rr][j][3] = astate[rj*5+4];
        jdat[rr][j][4] = amask[rj];
    }
    if (tid < 4) {
        int ri_ = r0 + tid;
        rowdat[tid][0] = astate[ri_*5+0];
        rowdat[tid][1] = astate[ri_*5+1];
        rowdat[tid][2] = astate[ri_*5+3];
        rowdat[tid][3] = astate[ri_*5+4];
        rowdat[tid][4] = amask[ri_];
    }
    float b2c = nr_b2[0];
    __syncthreads();

    // Phase B: pair scores+dots; thread = (j, c) with 8-way hidden/d split
    {
        int j = tid >> 3, c = tid & 7;
        float mlp[4], dtn[4], ddv[4];
        #pragma unroll
        for (int r = 0; r < 4; ++r) {
            float rpx = jdat[r][j][0] - rowdat[r][0];
            float rpy = jdat[r][j][1] - rowdat[r][1];
            float rvx = jdat[r][j][2] - rowdat[r][2];
            float rvy = jdat[r][j][3] - rowdat[r][3];
            float dd = sqrtf(rpx*rpx + rpy*rpy);
            int rj = ((b*Nn + j)*Tt + t0 + r);
            const float* ej = a_emb + (size_t)rj*Dd;
            float am = 0.f, ad = 0.f;
            #pragma unroll 4
            for (int u = 0; u < 16; ++u) {
                int hh = (u<<3) + c;
                float t1 = fmaf(rpx, w1n[hh], fmaf(rpy, w1n[Hh+hh],
                           fmaf(rvx, w1n[2*Hh+hh], fmaf(rvy, w1n[3*Hh+hh],
                           fmaf(dd,  w1n[4*Hh+hh], b1n[hh])))));
                t1 = fmaxf(t1, 0.f);
                am = fmaf(t1, w2n[hh], am);
                ad = fmaf(ei4[r][hh], ej[hh], ad);
            }
            am += __shfl_xor(am, 1); ad += __shfl_xor(ad, 1);
            am += __shfl_xor(am, 2); ad += __shfl_xor(ad, 2);
            am += __shfl_xor(am, 4); ad += __shfl_xor(ad, 4);
            mlp[r] = am; dtn[r] = ad; ddv[r] = dd;
        }
        if (c == 0) {
            #pragma unroll
            for (int r = 0; r < 4; ++r) {
                bool vi = rowdat[r][4] > 0.5f;
                bool vj = jdat[r][j][4] > 0.5f;
                bool ok = vi && vj && (ddv[r] <= 30.0f) && (j != i);
                lgn[r][j] = ok ? fmaf(dtn[r], RSQRT_D, b2c + mlp[r]) : -1e30f;
            }
        }
    }
    __syncthreads();

    // Phase C: softmax over 32 j, wave per row
    {
        int w = tid >> 6, lam = tid & 63;
        float x = (lam < Nn) ? lgn[w][lam] : -1e30f;
        float mxv = x;
        for (int off = 32; off; off >>= 1) mxv = fmaxf(mxv, __shfl_xor(mxv, off));
        float e = (x > -1e29f) ? expf(x - mxv) : 0.f;
        float sm = e;
        for (int off = 32; off; off >>= 1) sm += __shfl_xor(sm, off);
        float inv = 1.f / fmaxf(sm, 1e-9f);
        if (lam < Nn) lgn[w][lam] = e * inv;
    }
    __syncthreads();

    // Phase D: nbr ctx, j-range split between halves
    {
        int d = tid & 127, hf = tid >> 7;
        float acc[4] = {0.f,0.f,0.f,0.f};
        for (int jj = 0; jj < 16; ++jj) {
            int j2 = (hf<<4) + jj;
            #pragma unroll
            for (int r = 0; r < 4; ++r) {
                float v = a_emb[((size_t)((b*Nn + j2)*Tt + t0 + r))*Dd + d];
                acc[r] = fmaf(lgn[r][j2], v, acc[r]);
            }
        }
        if (hf == 1) {
            #pragma unroll
            for (int r = 0; r < 4; ++r) redn[r][d] = acc[r];
        }
        __syncthreads();
        if (hf == 0) {
            #pragma unroll
            for (int r = 0; r < 4; ++r) tau[r][2*Dd + d] = acc[r] + redn[r][d];
        }
    }
    __syncthreads();

    // Phase E: to layer1 — thread (h, rp) computes rows rp and rp+2
    {
        int h = tid & 127, rp = tid >> 7;
        float accA = 0.f, accB = 0.f;
        for (int k = 0; k < 3*Dd; ++k) {
            float w = to_w1[k*Hh + h];
            accA = fmaf(tau[rp][k],   w, accA);
            accB = fmaf(tau[rp+2][k], w, accB);
        }
        float bv = to_b1[h];
        g1s[rp][h]   = fmaxf(accA + bv, 0.f);
        g1s[rp+2][h] = fmaxf(accB + bv, 0.f);
    }
    __syncthreads();

    // Phase F: to layer2 — thread (o, row)
    {
        int o = tid & 63, row = tid >> 6;
        float acc = to_b2[o];
        for (int hh = 0; hh < Hh; ++hh) acc = fmaf(g1s[row][hh], to_w2[hh*TAUu + o], acc);
        float vi = (rowdat[row][4] > 0.5f) ? 1.f : 0.f;
        out[(r0+row)*TAUu + o] = acc * vi;
    }
}

extern "C" void kernel_launch(void* const* d_in, const int* in_sizes, int n_in,
                              void* d_out, int out_size, void* d_ws, size_t ws_size,
                              hipStream_t stream) {
    const float* agents_state  = (const float*)d_in[0];
    const float* agents_mask   = (const float*)d_in[1];
    const float* map_polylines = (const float*)d_in[2];
    const float* map_poly_mask = (const float*)d_in[3];
    const int*   map_poly_type = (const int*)d_in[4];
    const int*   map_tl_status = (const int*)d_in[5];
    const int*   map_on_route  = (const int*)d_in[6];
    const float* pm_w1 = (const float*)d_in[7];
    const float* pm_b1 = (const float*)d_in[8];
    const float* pm_w2 = (const float*)d_in[9];
    const float* pm_b2 = (const float*)d_in[10];
    const float* type_emb  = (const float*)d_in[11];
    const float* tl_emb    = (const float*)d_in[12];
    const float* route_emb = (const float*)d_in[13];
    const float* mo_w1 = (const float*)d_in[14];
    const float* mo_b1 = (const float*)d_in[15];
    const float* mo_w2 = (const float*)d_in[16];
    const float* mo_b2 = (const float*)d_in[17];
    const float* ae_w1 = (const float*)d_in[18];
    const float* ae_b1 = (const float*)d_in[19];
    const float* ae_w2 = (const float*)d_in[20];
    const float* ae_b2 = (const float*)d_in[21];
    const float* ae_w3 = (const float*)d_in[22];
    const float* ae_b3 = (const float*)d_in[23];
    const float* mr_w1 = (const float*)d_in[24];
    const float* mr_b1 = (const float*)d_in[25];
    const float* mr_w2 = (const float*)d_in[26];
    const float* mr_b2 = (const float*)d_in[27];
    const float* nr_w1 = (const float*)d_in[28];
    const float* nr_b1 = (const float*)d_in[29];
    const float* nr_w2 = (const float*)d_in[30];
    const float* nr_b2 = (const float*)d_in[31];
    const float* to_w1 = (const float*)d_in[32];
    const float* to_b1 = (const float*)d_in[33];
    const float* to_w2 = (const float*)d_in[34];
    const float* to_b2 = (const float*)d_in[35];

    float* ws = (float*)d_ws;
    float* map_node   = ws;                 // B*M*D   = 65536
    float* map_nodeT  = ws + 65536;         // B*D*M   = 65536
    float* map_center = ws + 131072;        // B*M*2   = 1024
    float* a_emb      = ws + 132096;        // B*N*T*D = 262144
    float* map_ctx    = ws + 394240;        // B*N*T*D = 262144

    float* out = (float*)d_out;

    k_map<<<Bb*Mm, 256, 0, stream>>>(map_polylines, map_poly_mask,
        map_poly_type, map_tl_status, map_on_route,
        pm_w1, pm_b1, pm_w2, pm_b2, type_emb, tl_emb, route_emb,
        mo_w1, mo_b1, mo_w2, mo_b2, map_node, map_nodeT, map_center);

    k_agent<<<Bb*Nn*Tt/4, 128, 0, stream>>>(agents_state, agents_mask,
        ae_w1, ae_b1, ae_w2, ae_b2, ae_w3, ae_b3, a_emb);

    k_mapattn<<<Bb*Nn*Tt/4, 256, 0, stream>>>(agents_state, map_poly_mask,
        a_emb, map_node, map_nodeT, map_center, mr_w1, mr_b1, mr_w2, mr_b2, map_ctx);

    k_nbr_out<<<Bb*Nn*Tt/4, 256, 0, stream>>>(agents_state, agents_mask,
        a_emb, map_ctx, nr_w1, nr_b1, nr_w2, nr_b2,
        to_w1, to_b1, to_w2, to_b2, out);
}